// Round 8
// baseline (464.989 us; speedup 1.0000x reference)
//
#include <hip/hip_runtime.h>
#include <hip/hip_bf16.h>

#define NT 8192
#define NS 8192
#define FD 128
#define PD 128
#define KTOP 2457                      /* max(1, int(8192*0.3)) */
#define TAUINV 14.285714285714286f     /* 1/0.07 */
#define HSIZE 65536
#define HMASK 65535
#define NMC 4096                       /* matched rows = N_S/2 by construction */

typedef __attribute__((ext_vector_type(8))) short s16x8;
typedef __attribute__((ext_vector_type(4))) float f32x4;

__device__ __forceinline__ float bf2f(unsigned short u) {
  return __uint_as_float(((unsigned)u) << 16);
}
__device__ __forceinline__ unsigned short f2bf(float x) {   // RNE
  unsigned u = __float_as_uint(x);
  return (unsigned short)((u + 0x7FFF + ((u >> 16) & 1)) >> 16);
}
// monotone bf16 bit-key: larger float <-> larger 16-bit key
__device__ __forceinline__ unsigned bf2key(unsigned short u) {
  return (u & 0x8000u) ? (unsigned)(u ^ 0xFFFFu) : (unsigned)(u ^ 0x8000u);
}
__device__ __forceinline__ float key2f(unsigned key) {
  unsigned u = (key & 0x8000u) ? (key ^ 0x8000u) : (key ^ 0xFFFFu);
  return __uint_as_float((u & 0xFFFFu) << 16);
}

// ---------------------------------------------------------------------------
__global__ __launch_bounds__(256) void init_ws(float* stats, int* hkey,
                                               int* nmatch, float* dsum,
                                               unsigned* dcnt)
{
  int i = blockIdx.x * 256 + threadIdx.x;
  if (i < 512) stats[i] = 0.f;
  if (i < HSIZE) hkey[i] = -1;
  if (i == 0) { *nmatch = 0; *dsum = 0.f; *dcnt = 0u; }
}

// ---------------------------------------------------------------------------
// Projection MLP (pre-BN) for BOTH nets: blockIdx.y = 0 teacher / 1 student.
// ---------------------------------------------------------------------------
__global__ __launch_bounds__(256) void proj_mlp2(
    const float* __restrict__ Xt, const float* __restrict__ Xs2,
    const float* __restrict__ tW1, const float* __restrict__ tB1,
    const float* __restrict__ tW2, const float* __restrict__ tB2,
    const float* __restrict__ sW1, const float* __restrict__ sB1,
    const float* __restrict__ sW2, const float* __restrict__ sB2,
    float* __restrict__ Ht, float* __restrict__ Hs2, float* __restrict__ stats)
{
  int f = blockIdx.y;
  const float* X  = f ? Xs2 : Xt;
  const float* W1 = f ? sW1 : tW1;
  const float* B1 = f ? sB1 : tB1;
  const float* W2 = f ? sW2 : tW2;
  const float* B2 = f ? sB2 : tB2;
  float* H        = f ? Hs2 : Ht;
  float* colsum   = stats + f * 256;
  float* colsq    = colsum + 128;

  __shared__ __align__(16) float Xs[32][128];
  __shared__ __align__(16) float H1s[32][128];
  __shared__ float cs[128], cq[128];
  int tid = threadIdx.x;
  int r0 = blockIdx.x * 32;
  for (int i = tid; i < 32 * 32; i += 256) {
    int r = i >> 5, q = i & 31;
    ((float4*)Xs[r])[q] = ((const float4*)(X + (size_t)(r0 + r) * FD))[q];
  }
  if (tid < 128) { cs[tid] = 0.f; cq[tid] = 0.f; }
  __syncthreads();

  int c  = (tid & 63) * 2;
  int rg = (tid >> 6) * 8;
  float a0[8], a1[8];
  #pragma unroll
  for (int r = 0; r < 8; ++r) { a0[r] = 0.f; a1[r] = 0.f; }
  for (int k = 0; k < FD; ++k) {
    float2 w = *(const float2*)(W1 + k * FD + c);
    #pragma unroll
    for (int r = 0; r < 8; ++r) {
      float x = Xs[rg + r][k];
      a0[r] = fmaf(x, w.x, a0[r]);
      a1[r] = fmaf(x, w.y, a1[r]);
    }
  }
  float2 b = *(const float2*)(B1 + c);
  #pragma unroll
  for (int r = 0; r < 8; ++r) {
    H1s[rg + r][c]     = fmaxf(a0[r] + b.x, 0.f);
    H1s[rg + r][c + 1] = fmaxf(a1[r] + b.y, 0.f);
  }
  __syncthreads();

  #pragma unroll
  for (int r = 0; r < 8; ++r) { a0[r] = 0.f; a1[r] = 0.f; }
  for (int k = 0; k < FD; ++k) {
    float2 w = *(const float2*)(W2 + k * PD + c);
    #pragma unroll
    for (int r = 0; r < 8; ++r) {
      float x = H1s[rg + r][k];
      a0[r] = fmaf(x, w.x, a0[r]);
      a1[r] = fmaf(x, w.y, a1[r]);
    }
  }
  b = *(const float2*)(B2 + c);
  float s0 = 0.f, s1 = 0.f, q0 = 0.f, q1 = 0.f;
  #pragma unroll
  for (int r = 0; r < 8; ++r) {
    float h0 = a0[r] + b.x, h1 = a1[r] + b.y;
    *(float2*)(H + (size_t)(r0 + rg + r) * PD + c) = make_float2(h0, h1);
    s0 += h0; s1 += h1; q0 += h0 * h0; q1 += h1 * h1;
  }
  atomicAdd(&cs[c], s0);     atomicAdd(&cs[c + 1], s1);
  atomicAdd(&cq[c], q0);     atomicAdd(&cq[c + 1], q1);
  __syncthreads();
  if (tid < 128) { atomicAdd(&colsum[tid], cs[tid]); atomicAdd(&colsq[tid], cq[tid]); }
}

// ---------------------------------------------------------------------------
// BN + row-L2-normalize -> split bf16, both nets (blockIdx.y flag).
// ---------------------------------------------------------------------------
__global__ __launch_bounds__(256) void bn_l2_2(
    const float* __restrict__ Ht, const float* __restrict__ Hs2,
    const float* __restrict__ stats,
    const float* __restrict__ t_gamma, const float* __restrict__ t_beta,
    const float* __restrict__ s_gamma, const float* __restrict__ s_beta,
    unsigned short* __restrict__ Th, unsigned short* __restrict__ Tl,
    unsigned short* __restrict__ ShC, unsigned short* __restrict__ SlC,
    const int* __restrict__ minv)
{
  int f = blockIdx.y;
  const float* H = f ? Hs2 : Ht;
  const float* colsum = stats + f * 256;
  const float* colsq  = colsum + 128;
  const float* gamma  = f ? s_gamma : t_gamma;
  const float* beta   = f ? s_beta : t_beta;
  unsigned short* Oh  = f ? ShC : Th;
  unsigned short* Ol  = f ? SlC : Tl;
  const float invN = 1.f / (float)NT;

  __shared__ float part[2][2];
  int half = threadIdx.x >> 7;
  int c    = threadIdx.x & 127;
  int wih  = (threadIdx.x >> 6) & 1;
  int row  = blockIdx.x * 2 + half;
  float mu  = colsum[c] * invN;
  float var = colsq[c] * invN - mu * mu;
  float inv = rsqrtf(var + 1e-5f);
  float y = (H[(size_t)row * PD + c] - mu) * inv * gamma[c] + beta[c];
  float sq = y * y;
  #pragma unroll
  for (int off = 32; off >= 1; off >>= 1) sq += __shfl_xor(sq, off, 64);
  if ((threadIdx.x & 63) == 0) part[half][wih] = sq;
  __syncthreads();
  float norm = sqrtf(part[half][0] + part[half][1]);
  float r = y / norm;
  int orow = f ? minv[row] : row;
  if (orow >= 0) {
    unsigned ub = __float_as_uint(r);
    float fhi = __uint_as_float(ub & 0xFFFF0000u);
    float lo  = r - fhi;
    Oh[(size_t)orow * PD + c] = (unsigned short)(ub >> 16);
    Ol[(size_t)orow * PD + c] = (unsigned short)(__float_as_uint(lo) >> 16);
  }
}

// ---------------------------------------------------------------------------
// Coordinate hash (teacher keys unique).  Lookup also compacts matched rows.
// ---------------------------------------------------------------------------
__device__ __forceinline__ int coord_key(int4 c) {
  return ((c.x * 64 + c.y) * 128 + c.z) * 128 + c.w;
}

__global__ __launch_bounds__(256) void hash_insert(
    const int* __restrict__ coords, int* __restrict__ hkey, int* __restrict__ hval)
{
  int t = blockIdx.x * 256 + threadIdx.x;
  if (t >= NT) return;
  int key = coord_key(((const int4*)coords)[t]);
  unsigned slot = (((unsigned)key * 2654435761u) >> 16) & HMASK;
  while (true) {
    int old = atomicCAS(&hkey[slot], -1, key);
    if (old == -1) { hval[slot] = t; break; }
    slot = (slot + 1) & HMASK;
  }
}

__global__ __launch_bounds__(256) void hash_lookup(
    const int* __restrict__ coords, const int* __restrict__ hkey,
    const int* __restrict__ hval, int* __restrict__ minv,
    int* __restrict__ mt, int* __restrict__ nmatch)
{
  int s = blockIdx.x * 256 + threadIdx.x;
  if (s >= NS) return;
  int key = coord_key(((const int4*)coords)[s]);
  unsigned slot = (((unsigned)key * 2654435761u) >> 16) & HMASK;
  int res = -1;
  while (true) {
    int k = hkey[slot];
    if (k == key) { res = hval[slot]; break; }
    if (k == -1) break;
    slot = (slot + 1) & HMASK;
  }
  int cslot = -1;
  if (res >= 0) { cslot = atomicAdd(nmatch, 1); mt[cslot] = res; }
  minv[s] = cslot;
}

// ---------------------------------------------------------------------------
// Split-bf16 MFMA GEMM -> bf16 P.  (unchanged from r7)
// ---------------------------------------------------------------------------
__device__ __forceinline__ void gload16(const void* g, void* l) {
  __builtin_amdgcn_global_load_lds(
      (const __attribute__((address_space(1))) unsigned int*)g,
      (__attribute__((address_space(3))) unsigned int*)l, 16, 0, 0);
}

__global__ __launch_bounds__(256) void gemm_bf16x2(
    const unsigned short* __restrict__ ShC, const unsigned short* __restrict__ SlC,
    const unsigned short* __restrict__ Th, const unsigned short* __restrict__ Tl,
    unsigned short* __restrict__ Pb, const int* __restrict__ nmatch)
{
  int ay = blockIdx.x, bx = blockIdx.y;        // x = A tile (fast dim)
  if (ay * 128 >= *nmatch) return;

  __shared__ unsigned short lds[32768];        // Bh 32KB | Bl 32KB
  int tid = threadIdx.x, lane = tid & 63, wid = tid >> 6;

  const unsigned short* gB[2] = { Th + (size_t)bx * 128 * FD,
                                  Tl + (size_t)bx * 128 * FD };
  #pragma unroll
  for (int comp = 0; comp < 2; ++comp) {
    const char* g = (const char*)gB[comp];
    char* lb = (char*)lds + comp * 32768;
    #pragma unroll
    for (int it = 0; it < 8; ++it) {
      int chunk0 = it * 256 + wid * 64;
      int d = (chunk0 + lane) * 16;
      int src = d ^ (((d >> 8) & 7) << 4);
      gload16(g + src, lb + chunk0 * 16);
    }
  }

  int wr = wid >> 1, wc = wid & 1;             // 2x2 waves of 64x64
  const unsigned short* gA_h = ShC + (size_t)(ay * 128) * FD;
  const unsigned short* gA_l = SlC + (size_t)(ay * 128) * FD;
  int rA[4];
  #pragma unroll
  for (int m = 0; m < 4; ++m) rA[m] = wr * 64 + m * 16 + (lane & 15);
  int cA0 = (lane >> 4) * 8;

  s16x8 nah[4], nal[4];                        // kk=0 prefetch
  #pragma unroll
  for (int m = 0; m < 4; ++m) {
    nah[m] = *(const s16x8*)(gA_h + (size_t)rA[m] * FD + cA0);
    nal[m] = *(const s16x8*)(gA_l + (size_t)rA[m] * FD + cA0);
  }
  __syncthreads();

  f32x4 acc[4][4] = {};
  #pragma unroll
  for (int kk = 0; kk < 4; ++kk) {
    s16x8 ah[4], al[4];
    #pragma unroll
    for (int m = 0; m < 4; ++m) { ah[m] = nah[m]; al[m] = nal[m]; }
    if (kk < 3) {
      int cA = (kk + 1) * 32 + cA0;
      #pragma unroll
      for (int m = 0; m < 4; ++m) {
        nah[m] = *(const s16x8*)(gA_h + (size_t)rA[m] * FD + cA);
        nal[m] = *(const s16x8*)(gA_l + (size_t)rA[m] * FD + cA);
      }
    }
    int cB = kk * 32 + cA0;
    s16x8 bh[4], bl[4];
    #pragma unroll
    for (int n = 0; n < 4; ++n) {
      int r = wc * 64 + n * 16 + (lane & 15);
      int byt = r * 256 + ((cB * 2) ^ ((r & 7) << 4));
      bh[n] = *(const s16x8*)((const char*)lds + byt);
      bl[n] = *(const s16x8*)((const char*)lds + 32768 + byt);
    }
    #pragma unroll
    for (int m = 0; m < 4; ++m)
      #pragma unroll
      for (int n = 0; n < 4; ++n) {
        acc[m][n] = __builtin_amdgcn_mfma_f32_16x16x32_bf16(ah[m], bh[n], acc[m][n], 0, 0, 0);
        acc[m][n] = __builtin_amdgcn_mfma_f32_16x16x32_bf16(ah[m], bl[n], acc[m][n], 0, 0, 0);
        acc[m][n] = __builtin_amdgcn_mfma_f32_16x16x32_bf16(al[m], bh[n], acc[m][n], 0, 0, 0);
      }
  }

  // C/D layout: col = lane&15, row = (lane>>4)*4 + reg
  #pragma unroll
  for (int m = 0; m < 4; ++m)
    #pragma unroll
    for (int n = 0; n < 4; ++n) {
      int pc = bx * 128 + wc * 64 + n * 16 + (lane & 15);
      int pr0 = ay * 128 + wr * 64 + m * 16 + (lane >> 4) * 4;
      #pragma unroll
      for (int reg = 0; reg < 4; ++reg)
        Pb[(size_t)(pr0 + reg) * NT + pc] = f2bf(acc[m][n][reg] * TAUINV);
    }
}

// ---------------------------------------------------------------------------
// Exact top-k + logsumexp via 2-pass radix on bf16 keys, row in registers.
// Fuses pos (wave 0, exact f32 dot) and final mean (atomic + last-block).
// ---------------------------------------------------------------------------
__global__ __launch_bounds__(256) void select_lse(
    const unsigned short* __restrict__ Pb,
    const unsigned short* __restrict__ ShC, const unsigned short* __restrict__ SlC,
    const unsigned short* __restrict__ Th, const unsigned short* __restrict__ Tl,
    const int* __restrict__ mt, const int* __restrict__ nmatch,
    float* __restrict__ dsum, unsigned* __restrict__ dcnt,
    float* __restrict__ out)
{
  __shared__ unsigned hist4[4 * 256];     // per-wave 256-bin histograms, 4 KB
  __shared__ unsigned wsum[4];
  __shared__ float redF[4];
  __shared__ unsigned redU[4];
  __shared__ int redI[4];
  __shared__ unsigned sh_Mk;
  __shared__ float sh_pos;
  __shared__ int sh_B1, sh_B2;
  __shared__ unsigned sh_j1;

  int tid = threadIdx.x, lane = tid & 63, wid = tid >> 6;
  int slot = blockIdx.x;
  int nm = *nmatch;
  bool active = slot < nm;

  if (active) {
    const unsigned short* p = Pb + (size_t)slot * NT;

    // ---- wave 0: exact f32 positive dot (128 elems, 2/lane) ----
    if (wid == 0) {
      int t = mt[slot];
      int k0 = lane * 2;
      float a0 = bf2f(ShC[(size_t)slot * FD + k0])     + bf2f(SlC[(size_t)slot * FD + k0]);
      float a1 = bf2f(ShC[(size_t)slot * FD + k0 + 1]) + bf2f(SlC[(size_t)slot * FD + k0 + 1]);
      float b0 = bf2f(Th[(size_t)t * FD + k0])         + bf2f(Tl[(size_t)t * FD + k0]);
      float b1 = bf2f(Th[(size_t)t * FD + k0 + 1])     + bf2f(Tl[(size_t)t * FD + k0 + 1]);
      float sum = fmaf(a1, b1, a0 * b0);
      #pragma unroll
      for (int off = 32; off >= 1; off >>= 1) sum += __shfl_xor(sum, off, 64);
      if (lane == 0) sh_pos = sum * TAUINV;
    }

    // ---- row -> monotone 16-bit keys in registers + max key ----
    unsigned kk[32];
    unsigned kmax = 0;
    #pragma unroll
    for (int q = 0; q < 4; ++q) {
      s16x8 v = ((const s16x8*)p)[tid + 256 * q];
      #pragma unroll
      for (int j = 0; j < 8; ++j) {
        unsigned key = bf2key((unsigned short)v[j]);
        kk[q * 8 + j] = key;
        kmax = key > kmax ? key : kmax;
      }
    }
    #pragma unroll
    for (int off = 32; off >= 1; off >>= 1) {
      unsigned o = __shfl_xor(kmax, off, 64);
      kmax = o > kmax ? o : kmax;
    }
    if (lane == 0) redU[wid] = kmax;
    __syncthreads();
    if (tid == 0) {
      unsigned m0 = redU[0] > redU[1] ? redU[0] : redU[1];
      unsigned m1 = redU[2] > redU[3] ? redU[2] : redU[3];
      sh_Mk = m0 > m1 ? m0 : m1;
    }

    // ---- pass 1: key high byte ----
    hist4[tid] = 0; hist4[tid + 256] = 0; hist4[tid + 512] = 0; hist4[tid + 768] = 0;
    __syncthreads();
    unsigned* wh = hist4 + (wid << 8);
    #pragma unroll
    for (int j = 0; j < 32; ++j) atomicAdd(&wh[kk[j] >> 8], 1u);
    __syncthreads();
    unsigned c0 = hist4[tid] + hist4[tid + 256] + hist4[tid + 512] + hist4[tid + 768];
    unsigned s = c0;
    #pragma unroll
    for (int off = 1; off <= 32; off <<= 1) {
      unsigned t2 = __shfl_down(s, off, 64);
      if (lane + off < 64) s += t2;
    }
    if (lane == 0) wsum[wid] = s;
    __syncthreads();
    unsigned add = 0;
    for (int w2 = wid + 1; w2 < 4; ++w2) add += wsum[w2];
    unsigned si = s + add, sn = si - c0;
    if (si >= (unsigned)KTOP && sn < (unsigned)KTOP) {
      sh_B1 = tid;
      sh_j1 = (unsigned)KTOP - sn;
    }
    __syncthreads();
    int B1 = sh_B1;
    unsigned j1 = sh_j1;

    // ---- pass 2: key low byte within bin B1 ----
    hist4[tid] = 0; hist4[tid + 256] = 0; hist4[tid + 512] = 0; hist4[tid + 768] = 0;
    __syncthreads();
    #pragma unroll
    for (int j = 0; j < 32; ++j)
      if ((int)(kk[j] >> 8) == B1) atomicAdd(&wh[kk[j] & 255], 1u);
    __syncthreads();
    c0 = hist4[tid] + hist4[tid + 256] + hist4[tid + 512] + hist4[tid + 768];
    s = c0;
    #pragma unroll
    for (int off = 1; off <= 32; off <<= 1) {
      unsigned t2 = __shfl_down(s, off, 64);
      if (lane + off < 64) s += t2;
    }
    if (lane == 0) wsum[wid] = s;
    __syncthreads();
    add = 0;
    for (int w2 = wid + 1; w2 < 4; ++w2) add += wsum[w2];
    si = s + add; sn = si - c0;
    if (si >= j1 && sn < j1) sh_B2 = tid;
    __syncthreads();

    unsigned kth = ((unsigned)sh_B1 << 8) | (unsigned)sh_B2;
    float theta = key2f(kth);
    float M = key2f(sh_Mk);
    float pos = sh_pos;
    float Mp = fmaxf(M, pos);

    // ---- exp-sum over strict top (float compare), ties via count ----
    float esum = 0.f; int g = 0;
    #pragma unroll
    for (int j = 0; j < 32; ++j) {
      float v = key2f(kk[j]);
      if (v > theta) { esum += __expf(v - Mp); g++; }
    }
    #pragma unroll
    for (int off = 32; off >= 1; off >>= 1) {
      esum += __shfl_xor(esum, off, 64);
      g    += __shfl_xor(g, off, 64);
    }
    if (lane == 0) { redF[wid] = esum; redI[wid] = g; }
    __syncthreads();
    if (tid == 0) {
      float E = redF[0] + redF[1] + redF[2] + redF[3];
      int   G = redI[0] + redI[1] + redI[2] + redI[3];
      float S = E + (float)(KTOP - G) * __expf(theta - Mp) + __expf(pos - Mp);
      atomicAdd(dsum, logf(S) + Mp - pos);
    }
  }

  // ---- last-block finalize: mean over matched rows ----
  __threadfence();
  if (tid == 0) {
    unsigned old = atomicAdd(dcnt, 1u);
    if (old == (unsigned)gridDim.x - 1u) {
      __threadfence();
      float S = *(volatile float*)dsum;
      out[0] = S / fmaxf((float)nm, 1.f);
    }
  }
}

// ---------------------------------------------------------------------------
extern "C" void kernel_launch(void* const* d_in, const int* in_sizes, int n_in,
                              void* d_out, int out_size, void* d_ws, size_t ws_size,
                              hipStream_t stream)
{
  const float* t_feat  = (const float*)d_in[0];
  const float* s_feat  = (const float*)d_in[1];
  const float* t_w1    = (const float*)d_in[2];
  const float* t_b1    = (const float*)d_in[3];
  const float* t_w2    = (const float*)d_in[4];
  const float* t_b2    = (const float*)d_in[5];
  const float* t_gamma = (const float*)d_in[6];
  const float* t_beta  = (const float*)d_in[7];
  const float* s_w1    = (const float*)d_in[8];
  const float* s_b1    = (const float*)d_in[9];
  const float* s_w2    = (const float*)d_in[10];
  const float* s_b2    = (const float*)d_in[11];
  const float* s_gamma = (const float*)d_in[12];
  const float* s_beta  = (const float*)d_in[13];
  const int*   t_coord = (const int*)d_in[14];
  const int*   s_coord = (const int*)d_in[15];

  // ws layout (bytes), ws_size = 256 MiB:
  //  0x000000 Th 2MB | 0x200000 Tl 2MB | 0x400000 ShC 2MB | 0x600000 SlC 2MB
  //  0x800000 stats 2KB | 0x800800 hkey 256KB | 0x840800 hval 256KB
  //  0x880800 nmatch | 0x880900 mt 32KB | 0x888900 minv 32KB
  //  0x890900 dsum 4B | 0x890908 dcnt 4B
  //  0x8B0000 Ht 4MB, Hs 4MB (dead after bn) -- Pb bf16 (64MB) aliases here
  char* w = (char*)d_ws;
  unsigned short* Th  = (unsigned short*)(w + 0x000000);
  unsigned short* Tl  = (unsigned short*)(w + 0x200000);
  unsigned short* ShC = (unsigned short*)(w + 0x400000);
  unsigned short* SlC = (unsigned short*)(w + 0x600000);
  float* stats  = (float*)(w + 0x800000);
  int*   hkey   = (int*)(w + 0x800800);
  int*   hval   = (int*)(w + 0x840800);
  int*   nmatch = (int*)(w + 0x880800);
  int*   mt     = (int*)(w + 0x880900);
  int*   minv   = (int*)(w + 0x888900);
  float* dsum   = (float*)(w + 0x890900);
  unsigned* dcnt = (unsigned*)(w + 0x890908);
  float* Ht     = (float*)(w + 0x8B0000);
  float* Hs     = (float*)(w + 0xCB0000);
  unsigned short* Pb = (unsigned short*)(w + 0x8B0000);  // aliases Ht/Hs

  init_ws<<<HSIZE / 256, 256, 0, stream>>>(stats, hkey, nmatch, dsum, dcnt);
  hash_insert<<<NT / 256, 256, 0, stream>>>(t_coord, hkey, hval);
  hash_lookup<<<NS / 256, 256, 0, stream>>>(s_coord, hkey, hval, minv, mt, nmatch);

  {
    dim3 g(NT / 32, 2);
    proj_mlp2<<<g, 256, 0, stream>>>(t_feat, s_feat,
                                     t_w1, t_b1, t_w2, t_b2,
                                     s_w1, s_b1, s_w2, s_b2,
                                     Ht, Hs, stats);
  }
  {
    dim3 g(NT / 2, 2);
    bn_l2_2<<<g, 256, 0, stream>>>(Ht, Hs, stats, t_gamma, t_beta,
                                   s_gamma, s_beta, Th, Tl, ShC, SlC, minv);
  }
  {
    dim3 g(NMC / 128, NT / 128);             // x = A tiles (fast), y = B tiles
    gemm_bf16x2<<<g, 256, 0, stream>>>(ShC, SlC, Th, Tl, Pb, nmatch);
  }
  select_lse<<<NMC, 256, 0, stream>>>(Pb, ShC, SlC, Th, Tl, mt, nmatch,
                                      dsum, dcnt, (float*)d_out);
}

// Round 9
// 443.317 us; speedup vs baseline: 1.0489x; 1.0489x over previous
//
#include <hip/hip_runtime.h>
#include <hip/hip_bf16.h>

#define NT 8192
#define NS 8192
#define FD 128
#define PD 128
#define KTOP 2457                      /* max(1, int(8192*0.3)) */
#define TAUINV 14.285714285714286f     /* 1/0.07 */
#define HSIZE 65536
#define HMASK 65535
#define NMC 4096                       /* matched rows = N_S/2 by construction */

typedef __attribute__((ext_vector_type(8))) short s16x8;
typedef __attribute__((ext_vector_type(4))) float f32x4;

__device__ __forceinline__ float bf2f(unsigned short u) {
  return __uint_as_float(((unsigned)u) << 16);
}
__device__ __forceinline__ unsigned short f2bf(float x) {   // RNE
  unsigned u = __float_as_uint(x);
  return (unsigned short)((u + 0x7FFF + ((u >> 16) & 1)) >> 16);
}
// monotone bf16 bit-key: larger float <-> larger 16-bit key
__device__ __forceinline__ unsigned bf2key(unsigned short u) {
  return (u & 0x8000u) ? (unsigned)(u ^ 0xFFFFu) : (unsigned)(u ^ 0x8000u);
}
__device__ __forceinline__ float key2f(unsigned key) {
  unsigned u = (key & 0x8000u) ? (key ^ 0x8000u) : (key ^ 0xFFFFu);
  return __uint_as_float((u & 0xFFFFu) << 16);
}

// ---------------------------------------------------------------------------
__global__ __launch_bounds__(256) void init_ws(float* stats, int* hkey,
                                               int* nmatch, float* dsum,
                                               unsigned* dcnt)
{
  int i = blockIdx.x * 256 + threadIdx.x;
  if (i < 512) stats[i] = 0.f;
  if (i < HSIZE) hkey[i] = -1;
  if (i == 0) { *nmatch = 0; *dsum = 0.f; *dcnt = 0u; }
}

// ---------------------------------------------------------------------------
// Projection MLP (pre-BN) for BOTH nets: blockIdx.y = 0 teacher / 1 student.
// ---------------------------------------------------------------------------
__global__ __launch_bounds__(256) void proj_mlp2(
    const float* __restrict__ Xt, const float* __restrict__ Xs2,
    const float* __restrict__ tW1, const float* __restrict__ tB1,
    const float* __restrict__ tW2, const float* __restrict__ tB2,
    const float* __restrict__ sW1, const float* __restrict__ sB1,
    const float* __restrict__ sW2, const float* __restrict__ sB2,
    float* __restrict__ Ht, float* __restrict__ Hs2, float* __restrict__ stats)
{
  int f = blockIdx.y;
  const float* X  = f ? Xs2 : Xt;
  const float* W1 = f ? sW1 : tW1;
  const float* B1 = f ? sB1 : tB1;
  const float* W2 = f ? sW2 : tW2;
  const float* B2 = f ? sB2 : tB2;
  float* H        = f ? Hs2 : Ht;
  float* colsum   = stats + f * 256;
  float* colsq    = colsum + 128;

  __shared__ __align__(16) float Xs[32][128];
  __shared__ __align__(16) float H1s[32][128];
  __shared__ float cs[128], cq[128];
  int tid = threadIdx.x;
  int r0 = blockIdx.x * 32;
  for (int i = tid; i < 32 * 32; i += 256) {
    int r = i >> 5, q = i & 31;
    ((float4*)Xs[r])[q] = ((const float4*)(X + (size_t)(r0 + r) * FD))[q];
  }
  if (tid < 128) { cs[tid] = 0.f; cq[tid] = 0.f; }
  __syncthreads();

  int c  = (tid & 63) * 2;
  int rg = (tid >> 6) * 8;
  float a0[8], a1[8];
  #pragma unroll
  for (int r = 0; r < 8; ++r) { a0[r] = 0.f; a1[r] = 0.f; }
  for (int k = 0; k < FD; ++k) {
    float2 w = *(const float2*)(W1 + k * FD + c);
    #pragma unroll
    for (int r = 0; r < 8; ++r) {
      float x = Xs[rg + r][k];
      a0[r] = fmaf(x, w.x, a0[r]);
      a1[r] = fmaf(x, w.y, a1[r]);
    }
  }
  float2 b = *(const float2*)(B1 + c);
  #pragma unroll
  for (int r = 0; r < 8; ++r) {
    H1s[rg + r][c]     = fmaxf(a0[r] + b.x, 0.f);
    H1s[rg + r][c + 1] = fmaxf(a1[r] + b.y, 0.f);
  }
  __syncthreads();

  #pragma unroll
  for (int r = 0; r < 8; ++r) { a0[r] = 0.f; a1[r] = 0.f; }
  for (int k = 0; k < FD; ++k) {
    float2 w = *(const float2*)(W2 + k * PD + c);
    #pragma unroll
    for (int r = 0; r < 8; ++r) {
      float x = H1s[rg + r][k];
      a0[r] = fmaf(x, w.x, a0[r]);
      a1[r] = fmaf(x, w.y, a1[r]);
    }
  }
  b = *(const float2*)(B2 + c);
  float s0 = 0.f, s1 = 0.f, q0 = 0.f, q1 = 0.f;
  #pragma unroll
  for (int r = 0; r < 8; ++r) {
    float h0 = a0[r] + b.x, h1 = a1[r] + b.y;
    *(float2*)(H + (size_t)(r0 + rg + r) * PD + c) = make_float2(h0, h1);
    s0 += h0; s1 += h1; q0 += h0 * h0; q1 += h1 * h1;
  }
  atomicAdd(&cs[c], s0);     atomicAdd(&cs[c + 1], s1);
  atomicAdd(&cq[c], q0);     atomicAdd(&cq[c + 1], q1);
  __syncthreads();
  if (tid < 128) { atomicAdd(&colsum[tid], cs[tid]); atomicAdd(&colsq[tid], cq[tid]); }
}

// ---------------------------------------------------------------------------
// BN + row-L2-normalize -> split bf16, both nets (blockIdx.y flag).
// ---------------------------------------------------------------------------
__global__ __launch_bounds__(256) void bn_l2_2(
    const float* __restrict__ Ht, const float* __restrict__ Hs2,
    const float* __restrict__ stats,
    const float* __restrict__ t_gamma, const float* __restrict__ t_beta,
    const float* __restrict__ s_gamma, const float* __restrict__ s_beta,
    unsigned short* __restrict__ Th, unsigned short* __restrict__ Tl,
    unsigned short* __restrict__ ShC, unsigned short* __restrict__ SlC,
    const int* __restrict__ minv)
{
  int f = blockIdx.y;
  const float* H = f ? Hs2 : Ht;
  const float* colsum = stats + f * 256;
  const float* colsq  = colsum + 128;
  const float* gamma  = f ? s_gamma : t_gamma;
  const float* beta   = f ? s_beta : t_beta;
  unsigned short* Oh  = f ? ShC : Th;
  unsigned short* Ol  = f ? SlC : Tl;
  const float invN = 1.f / (float)NT;

  __shared__ float part[2][2];
  int half = threadIdx.x >> 7;
  int c    = threadIdx.x & 127;
  int wih  = (threadIdx.x >> 6) & 1;
  int row  = blockIdx.x * 2 + half;
  float mu  = colsum[c] * invN;
  float var = colsq[c] * invN - mu * mu;
  float inv = rsqrtf(var + 1e-5f);
  float y = (H[(size_t)row * PD + c] - mu) * inv * gamma[c] + beta[c];
  float sq = y * y;
  #pragma unroll
  for (int off = 32; off >= 1; off >>= 1) sq += __shfl_xor(sq, off, 64);
  if ((threadIdx.x & 63) == 0) part[half][wih] = sq;
  __syncthreads();
  float norm = sqrtf(part[half][0] + part[half][1]);
  float r = y / norm;
  int orow = f ? minv[row] : row;
  if (orow >= 0) {
    unsigned ub = __float_as_uint(r);
    float fhi = __uint_as_float(ub & 0xFFFF0000u);
    float lo  = r - fhi;
    Oh[(size_t)orow * PD + c] = (unsigned short)(ub >> 16);
    Ol[(size_t)orow * PD + c] = (unsigned short)(__float_as_uint(lo) >> 16);
  }
}

// ---------------------------------------------------------------------------
// Coordinate hash (teacher keys unique).  Lookup also compacts matched rows.
// ---------------------------------------------------------------------------
__device__ __forceinline__ int coord_key(int4 c) {
  return ((c.x * 64 + c.y) * 128 + c.z) * 128 + c.w;
}

__global__ __launch_bounds__(256) void hash_insert(
    const int* __restrict__ coords, int* __restrict__ hkey, int* __restrict__ hval)
{
  int t = blockIdx.x * 256 + threadIdx.x;
  if (t >= NT) return;
  int key = coord_key(((const int4*)coords)[t]);
  unsigned slot = (((unsigned)key * 2654435761u) >> 16) & HMASK;
  while (true) {
    int old = atomicCAS(&hkey[slot], -1, key);
    if (old == -1) { hval[slot] = t; break; }
    slot = (slot + 1) & HMASK;
  }
}

__global__ __launch_bounds__(256) void hash_lookup(
    const int* __restrict__ coords, const int* __restrict__ hkey,
    const int* __restrict__ hval, int* __restrict__ minv,
    int* __restrict__ mt, int* __restrict__ nmatch)
{
  int s = blockIdx.x * 256 + threadIdx.x;
  if (s >= NS) return;
  int key = coord_key(((const int4*)coords)[s]);
  unsigned slot = (((unsigned)key * 2654435761u) >> 16) & HMASK;
  int res = -1;
  while (true) {
    int k = hkey[slot];
    if (k == key) { res = hval[slot]; break; }
    if (k == -1) break;
    slot = (slot + 1) & HMASK;
  }
  int cslot = -1;
  if (res >= 0) { cslot = atomicAdd(nmatch, 1); mt[cslot] = res; }
  minv[s] = cslot;
}

// ---------------------------------------------------------------------------
// Split-bf16 MFMA GEMM -> bf16 P.  (unchanged, proven r6-r8)
// ---------------------------------------------------------------------------
__device__ __forceinline__ void gload16(const void* g, void* l) {
  __builtin_amdgcn_global_load_lds(
      (const __attribute__((address_space(1))) unsigned int*)g,
      (__attribute__((address_space(3))) unsigned int*)l, 16, 0, 0);
}

__global__ __launch_bounds__(256) void gemm_bf16x2(
    const unsigned short* __restrict__ ShC, const unsigned short* __restrict__ SlC,
    const unsigned short* __restrict__ Th, const unsigned short* __restrict__ Tl,
    unsigned short* __restrict__ Pb, const int* __restrict__ nmatch)
{
  int ay = blockIdx.x, bx = blockIdx.y;        // x = A tile (fast dim)
  if (ay * 128 >= *nmatch) return;

  __shared__ unsigned short lds[32768];        // Bh 32KB | Bl 32KB
  int tid = threadIdx.x, lane = tid & 63, wid = tid >> 6;

  const unsigned short* gB[2] = { Th + (size_t)bx * 128 * FD,
                                  Tl + (size_t)bx * 128 * FD };
  #pragma unroll
  for (int comp = 0; comp < 2; ++comp) {
    const char* g = (const char*)gB[comp];
    char* lb = (char*)lds + comp * 32768;
    #pragma unroll
    for (int it = 0; it < 8; ++it) {
      int chunk0 = it * 256 + wid * 64;
      int d = (chunk0 + lane) * 16;
      int src = d ^ (((d >> 8) & 7) << 4);
      gload16(g + src, lb + chunk0 * 16);
    }
  }

  int wr = wid >> 1, wc = wid & 1;             // 2x2 waves of 64x64
  const unsigned short* gA_h = ShC + (size_t)(ay * 128) * FD;
  const unsigned short* gA_l = SlC + (size_t)(ay * 128) * FD;
  int rA[4];
  #pragma unroll
  for (int m = 0; m < 4; ++m) rA[m] = wr * 64 + m * 16 + (lane & 15);
  int cA0 = (lane >> 4) * 8;

  s16x8 nah[4], nal[4];                        // kk=0 prefetch
  #pragma unroll
  for (int m = 0; m < 4; ++m) {
    nah[m] = *(const s16x8*)(gA_h + (size_t)rA[m] * FD + cA0);
    nal[m] = *(const s16x8*)(gA_l + (size_t)rA[m] * FD + cA0);
  }
  __syncthreads();

  f32x4 acc[4][4] = {};
  #pragma unroll
  for (int kk = 0; kk < 4; ++kk) {
    s16x8 ah[4], al[4];
    #pragma unroll
    for (int m = 0; m < 4; ++m) { ah[m] = nah[m]; al[m] = nal[m]; }
    if (kk < 3) {
      int cA = (kk + 1) * 32 + cA0;
      #pragma unroll
      for (int m = 0; m < 4; ++m) {
        nah[m] = *(const s16x8*)(gA_h + (size_t)rA[m] * FD + cA);
        nal[m] = *(const s16x8*)(gA_l + (size_t)rA[m] * FD + cA);
      }
    }
    int cB = kk * 32 + cA0;
    s16x8 bh[4], bl[4];
    #pragma unroll
    for (int n = 0; n < 4; ++n) {
      int r = wc * 64 + n * 16 + (lane & 15);
      int byt = r * 256 + ((cB * 2) ^ ((r & 7) << 4));
      bh[n] = *(const s16x8*)((const char*)lds + byt);
      bl[n] = *(const s16x8*)((const char*)lds + 32768 + byt);
    }
    #pragma unroll
    for (int m = 0; m < 4; ++m)
      #pragma unroll
      for (int n = 0; n < 4; ++n) {
        acc[m][n] = __builtin_amdgcn_mfma_f32_16x16x32_bf16(ah[m], bh[n], acc[m][n], 0, 0, 0);
        acc[m][n] = __builtin_amdgcn_mfma_f32_16x16x32_bf16(ah[m], bl[n], acc[m][n], 0, 0, 0);
        acc[m][n] = __builtin_amdgcn_mfma_f32_16x16x32_bf16(al[m], bh[n], acc[m][n], 0, 0, 0);
      }
  }

  // C/D layout: col = lane&15, row = (lane>>4)*4 + reg
  #pragma unroll
  for (int m = 0; m < 4; ++m)
    #pragma unroll
    for (int n = 0; n < 4; ++n) {
      int pc = bx * 128 + wc * 64 + n * 16 + (lane & 15);
      int pr0 = ay * 128 + wr * 64 + m * 16 + (lane >> 4) * 4;
      #pragma unroll
      for (int reg = 0; reg < 4; ++reg)
        Pb[(size_t)(pr0 + reg) * NT + pc] = f2bf(acc[m][n][reg] * TAUINV);
    }
}

// ---------------------------------------------------------------------------
// Exact top-k + logsumexp. k-th largest bf16 key found by 16-step binary
// search over the monotone key space: per-step count is pure register
// compares + wave shfl reduce (NO LDS histograms, NO atomics -- r8's radix
// binning serialized on same-address LDS atomicAdd because bf16 high bytes
// concentrate into ~16 bins). Fused pos (wave 0) + final mean (last block).
// ---------------------------------------------------------------------------
__global__ __launch_bounds__(256) void select_lse(
    const unsigned short* __restrict__ Pb,
    const unsigned short* __restrict__ ShC, const unsigned short* __restrict__ SlC,
    const unsigned short* __restrict__ Th, const unsigned short* __restrict__ Tl,
    const int* __restrict__ mt, const int* __restrict__ nmatch,
    float* __restrict__ dsum, unsigned* __restrict__ dcnt,
    float* __restrict__ out)
{
  __shared__ unsigned wcnt[2][4];         // double-buffered wave counts
  __shared__ float redF[4];
  __shared__ unsigned redU[4];
  __shared__ int redI[4];
  __shared__ float sh_pos;

  int tid = threadIdx.x, lane = tid & 63, wid = tid >> 6;
  int slot = blockIdx.x;
  int nm = *nmatch;
  bool active = slot < nm;

  if (active) {
    const unsigned short* p = Pb + (size_t)slot * NT;

    // ---- wave 0: exact f32 positive dot (128 elems, 2/lane) ----
    if (wid == 0) {
      int t = mt[slot];
      int k0 = lane * 2;
      float a0 = bf2f(ShC[(size_t)slot * FD + k0])     + bf2f(SlC[(size_t)slot * FD + k0]);
      float a1 = bf2f(ShC[(size_t)slot * FD + k0 + 1]) + bf2f(SlC[(size_t)slot * FD + k0 + 1]);
      float b0 = bf2f(Th[(size_t)t * FD + k0])         + bf2f(Tl[(size_t)t * FD + k0]);
      float b1 = bf2f(Th[(size_t)t * FD + k0 + 1])     + bf2f(Tl[(size_t)t * FD + k0 + 1]);
      float sum = fmaf(a1, b1, a0 * b0);
      #pragma unroll
      for (int off = 32; off >= 1; off >>= 1) sum += __shfl_xor(sum, off, 64);
      if (lane == 0) sh_pos = sum * TAUINV;
    }

    // ---- row -> monotone 16-bit keys in registers + max key ----
    unsigned kk[32];
    unsigned kmax = 0;
    #pragma unroll
    for (int q = 0; q < 4; ++q) {
      s16x8 v = ((const s16x8*)p)[tid + 256 * q];
      #pragma unroll
      for (int j = 0; j < 8; ++j) {
        unsigned key = bf2key((unsigned short)v[j]);
        kk[q * 8 + j] = key;
        kmax = key > kmax ? key : kmax;
      }
    }
    #pragma unroll
    for (int off = 32; off >= 1; off >>= 1) {
      unsigned o = __shfl_xor(kmax, off, 64);
      kmax = o > kmax ? o : kmax;
    }
    if (lane == 0) redU[wid] = kmax;

    // ---- binary search: largest key t with cnt_ge(t) >= KTOP ----
    unsigned lo = 0, hi = 65535;
    #pragma unroll 1
    for (int it = 0; it < 16; ++it) {
      unsigned mid = (lo + hi + 1) >> 1;
      int c = 0;
      #pragma unroll
      for (int j = 0; j < 32; ++j) c += (kk[j] >= mid) ? 1 : 0;
      #pragma unroll
      for (int off = 32; off >= 1; off >>= 1) c += __shfl_xor(c, off, 64);
      int buf = it & 1;
      if (lane == 0) wcnt[buf][wid] = (unsigned)c;
      __syncthreads();
      unsigned tot = wcnt[buf][0] + wcnt[buf][1] + wcnt[buf][2] + wcnt[buf][3];
      if (tot >= (unsigned)KTOP) lo = mid; else hi = mid - 1;
    }

    float theta = key2f(lo);
    float M = key2f(max(max(redU[0], redU[1]), max(redU[2], redU[3])));
    float pos = sh_pos;
    float Mp = fmaxf(M, pos);

    // ---- exp-sum over strict top (float compare), ties via count ----
    float esum = 0.f; int g = 0;
    #pragma unroll
    for (int j = 0; j < 32; ++j) {
      float v = key2f(kk[j]);
      if (v > theta) { esum += __expf(v - Mp); g++; }
    }
    #pragma unroll
    for (int off = 32; off >= 1; off >>= 1) {
      esum += __shfl_xor(esum, off, 64);
      g    += __shfl_xor(g, off, 64);
    }
    if (lane == 0) { redF[wid] = esum; redI[wid] = g; }
    __syncthreads();
    if (tid == 0) {
      float E = redF[0] + redF[1] + redF[2] + redF[3];
      int   G = redI[0] + redI[1] + redI[2] + redI[3];
      float S = E + (float)(KTOP - G) * __expf(theta - Mp) + __expf(pos - Mp);
      atomicAdd(dsum, logf(S) + Mp - pos);
    }
  }

  // ---- last-block finalize: mean over matched rows ----
  __threadfence();
  if (tid == 0) {
    unsigned old = atomicAdd(dcnt, 1u);
    if (old == (unsigned)gridDim.x - 1u) {
      __threadfence();
      float S = *(volatile float*)dsum;
      out[0] = S / fmaxf((float)nm, 1.f);
    }
  }
}

// ---------------------------------------------------------------------------
extern "C" void kernel_launch(void* const* d_in, const int* in_sizes, int n_in,
                              void* d_out, int out_size, void* d_ws, size_t ws_size,
                              hipStream_t stream)
{
  const float* t_feat  = (const float*)d_in[0];
  const float* s_feat  = (const float*)d_in[1];
  const float* t_w1    = (const float*)d_in[2];
  const float* t_b1    = (const float*)d_in[3];
  const float* t_w2    = (const float*)d_in[4];
  const float* t_b2    = (const float*)d_in[5];
  const float* t_gamma = (const float*)d_in[6];
  const float* t_beta  = (const float*)d_in[7];
  const float* s_w1    = (const float*)d_in[8];
  const float* s_b1    = (const float*)d_in[9];
  const float* s_w2    = (const float*)d_in[10];
  const float* s_b2    = (const float*)d_in[11];
  const float* s_gamma = (const float*)d_in[12];
  const float* s_beta  = (const float*)d_in[13];
  const int*   t_coord = (const int*)d_in[14];
  const int*   s_coord = (const int*)d_in[15];

  // ws layout (bytes), ws_size = 256 MiB:
  //  0x000000 Th 2MB | 0x200000 Tl 2MB | 0x400000 ShC 2MB | 0x600000 SlC 2MB
  //  0x800000 stats 2KB | 0x800800 hkey 256KB | 0x840800 hval 256KB
  //  0x880800 nmatch | 0x880900 mt 32KB | 0x888900 minv 32KB
  //  0x890900 dsum 4B | 0x890908 dcnt 4B
  //  0x8B0000 Ht 4MB, Hs 4MB (dead after bn) -- Pb bf16 (64MB) aliases here
  char* w = (char*)d_ws;
  unsigned short* Th  = (unsigned short*)(w + 0x000000);
  unsigned short* Tl  = (unsigned short*)(w + 0x200000);
  unsigned short* ShC = (unsigned short*)(w + 0x400000);
  unsigned short* SlC = (unsigned short*)(w + 0x600000);
  float* stats  = (float*)(w + 0x800000);
  int*   hkey   = (int*)(w + 0x800800);
  int*   hval   = (int*)(w + 0x840800);
  int*   nmatch = (int*)(w + 0x880800);
  int*   mt     = (int*)(w + 0x880900);
  int*   minv   = (int*)(w + 0x888900);
  float* dsum   = (float*)(w + 0x890900);
  unsigned* dcnt = (unsigned*)(w + 0x890908);
  float* Ht     = (float*)(w + 0x8B0000);
  float* Hs     = (float*)(w + 0xCB0000);
  unsigned short* Pb = (unsigned short*)(w + 0x8B0000);  // aliases Ht/Hs

  init_ws<<<HSIZE / 256, 256, 0, stream>>>(stats, hkey, nmatch, dsum, dcnt);
  hash_insert<<<NT / 256, 256, 0, stream>>>(t_coord, hkey, hval);
  hash_lookup<<<NS / 256, 256, 0, stream>>>(s_coord, hkey, hval, minv, mt, nmatch);

  {
    dim3 g(NT / 32, 2);
    proj_mlp2<<<g, 256, 0, stream>>>(t_feat, s_feat,
                                     t_w1, t_b1, t_w2, t_b2,
                                     s_w1, s_b1, s_w2, s_b2,
                                     Ht, Hs, stats);
  }
  {
    dim3 g(NT / 2, 2);
    bn_l2_2<<<g, 256, 0, stream>>>(Ht, Hs, stats, t_gamma, t_beta,
                                   s_gamma, s_beta, Th, Tl, ShC, SlC, minv);
  }
  {
    dim3 g(NMC / 128, NT / 128);             // x = A tiles (fast), y = B tiles
    gemm_bf16x2<<<g, 256, 0, stream>>>(ShC, SlC, Th, Tl, Pb, nmatch);
  }
  select_lse<<<NMC, 256, 0, stream>>>(Pb, ShC, SlC, Th, Tl, mt, nmatch,
                                      dsum, dcnt, (float*)d_out);
}